// Round 11
// baseline (69.427 us; speedup 1.0000x reference)
//
#include <hip/hip_runtime.h>
#include <hip/hip_bf16.h>

#define BCH 32   // B*C heads
#define NN  2048
#define DD  64   // F = H = O

typedef __attribute__((ext_vector_type(8)))  __bf16 bf16x8;
typedef __attribute__((ext_vector_type(4)))  __bf16 bf16x4;
typedef __attribute__((ext_vector_type(4)))  float  f32x4;
typedef __attribute__((ext_vector_type(16))) float  f32x16;
typedef __attribute__((ext_vector_type(2)))  int    i32x2;
typedef __attribute__((ext_vector_type(4)))  int    i32x4;
typedef __attribute__((ext_vector_type(2)))  unsigned int u32x2;

__device__ inline f32x4 mfma16(bf16x8 a, bf16x8 b, f32x4 c) {
    return __builtin_amdgcn_mfma_f32_16x16x32_bf16(a, b, c, 0, 0, 0);
}
__device__ inline f32x16 mfma32(bf16x8 a, bf16x8 b, f32x16 c) {
    return __builtin_amdgcn_mfma_f32_32x32x16_bf16(a, b, c, 0, 0, 0);
}
__device__ inline void gload16(const void* g, void* l) {
    __builtin_amdgcn_global_load_lds(
        (const __attribute__((address_space(1))) void*)g,
        (__attribute__((address_space(3))) void*)l, 16, 0, 0);
}
// permlane32_swap BUILTIN (validated round 9; inline-asm version caused
// nondeterministic corruption -> MFMA-operand hazard not inserted).
__device__ inline void plswap(int& a, int& b) {
    u32x2 r = __builtin_amdgcn_permlane32_swap((unsigned)a, (unsigned)b, false, false);
    a = (int)r[0];
    b = (int)r[1];
}

// ---------------------------------------------------------------------------
// Kernel 1 (unchanged, validated rounds 6-10): e1/e2 [bc][n][h], vT [bc][o][n]
// ---------------------------------------------------------------------------
__global__ __launch_bounds__(256) void prep_kernel(
    const float* __restrict__ x,
    const float* __restrict__ W1, const float* __restrict__ b1,
    const float* __restrict__ W2, const float* __restrict__ b2,
    const float* __restrict__ W3,
    __bf16* __restrict__ e1, __bf16* __restrict__ e2, __bf16* __restrict__ vT)
{
    const int t   = threadIdx.x;
    const int blk = blockIdx.x;
    const int bc  = blk >> 5, st = blk & 31;
    const long grow = (long)bc * NN + st * 64;
    const int w = t >> 6, l = t & 63, lg = l >> 4, li = l & 15;

    bf16x8 a[4][2];
    #pragma unroll
    for (int nb = 0; nb < 4; ++nb)
        #pragma unroll
        for (int kk = 0; kk < 2; ++kk) {
            const float* p = x + (grow + nb * 16 + li) * DD + kk * 32 + lg * 8;
            f32x4 v0 = *(const f32x4*)p, v1 = *(const f32x4*)(p + 4);
            #pragma unroll
            for (int j = 0; j < 4; ++j) {
                a[nb][kk][j]     = (__bf16)v0[j];
                a[nb][kk][4 + j] = (__bf16)v1[j];
            }
        }

    bf16x8 wf1[2], wf2[2], wf3[2];
    #pragma unroll
    for (int kk = 0; kk < 2; ++kk) {
        const float* p1 = W1 + (w * 16 + li) * DD + kk * 32 + lg * 8;
        const float* p2 = W2 + (w * 16 + li) * DD + kk * 32 + lg * 8;
        const float* p3 = W3 + (w * 16 + li) * DD + kk * 32 + lg * 8;
        f32x4 u0 = *(const f32x4*)p1, u1 = *(const f32x4*)(p1 + 4);
        f32x4 v0 = *(const f32x4*)p2, v1 = *(const f32x4*)(p2 + 4);
        f32x4 t0 = *(const f32x4*)p3, t1 = *(const f32x4*)(p3 + 4);
        #pragma unroll
        for (int j = 0; j < 4; ++j) {
            wf1[kk][j] = (__bf16)u0[j]; wf1[kk][4 + j] = (__bf16)u1[j];
            wf2[kk][j] = (__bf16)v0[j]; wf2[kk][4 + j] = (__bf16)v1[j];
            wf3[kk][j] = (__bf16)t0[j]; wf3[kk][4 + j] = (__bf16)t1[j];
        }
    }
    const f32x4 bq1 = *(const f32x4*)(b1 + w * 16 + lg * 4);
    const f32x4 bq2 = *(const f32x4*)(b2 + w * 16 + lg * 4);

    #pragma unroll
    for (int nb = 0; nb < 4; ++nb) {
        f32x4 acc1 = {0.f,0.f,0.f,0.f}, acc2 = {0.f,0.f,0.f,0.f}, acc3 = {0.f,0.f,0.f,0.f};
        #pragma unroll
        for (int kk = 0; kk < 2; ++kk) {
            acc1 = mfma16(wf1[kk], a[nb][kk], acc1);   // D[h][n]
            acc2 = mfma16(wf2[kk], a[nb][kk], acc2);   // D[h][n]
            acc3 = mfma16(a[nb][kk], wf3[kk], acc3);   // D[n][o]
        }
        bf16x4 q1, q2, q3;
        #pragma unroll
        for (int r = 0; r < 4; ++r) {
            q1[r] = (__bf16)(acc1[r] + bq1[r]);
            q2[r] = (__bf16)(acc2[r] + bq2[r]);
            q3[r] = (__bf16)acc3[r];
        }
        *(bf16x4*)&e1[(grow + nb * 16 + li) * DD + w * 16 + lg * 4] = q1;
        *(bf16x4*)&e2[(grow + nb * 16 + li) * DD + w * 16 + lg * 4] = q2;
        *(bf16x4*)&vT[((long)bc * DD + w * 16 + li) * NN + st * 64 + nb * 16 + lg * 4] = q3;
    }
}

// ---------------------------------------------------------------------------
// Kernel 2: out = relu(e1 e2^T) v + b3. High-TLP m-split flash:
// grid 1024 (XCD-grouped: 32 nt x 32 bc), block 256 = 4 waves = 2 n-waves
// (32 n each) x 2 m-waves. 4 blocks/CU -> 16 waves/CU (4/SIMD), 4 independent
// barrier domains. Counted vmcnt(4), setprio MFMA clusters, permlane PV,
// loop-invariant zero accumulator seed.
// ---------------------------------------------------------------------------
__global__ __launch_bounds__(256, 4) void fused_kernel(
    const __bf16* __restrict__ e1, const __bf16* __restrict__ e2,
    const __bf16* __restrict__ vT, const float* __restrict__ b3,
    float* __restrict__ out)
{
    __shared__ __align__(16) unsigned char smem[32768];
    __bf16* e2t = (__bf16*)smem;             // [2][4096] bf16: [m][h] swizzled
    __bf16* vTt = (__bf16*)(smem + 16384);   // [2][4096] bf16: [o][m] swizzled
    float*  scratch = (float*)smem;          // epilogue reuse (16KB of 32KB)

    const int t   = threadIdx.x;
    const int bid = blockIdx.x;
    // XCD grouping (round-9-validated): each XCD owns 4 whole heads
    const int x8 = bid & 7, jj = bid >> 3;          // jj in 0..127
    const int bc = x8 * 4 + (jj >> 5), nt = jj & 31;

    const int w = t >> 6, l = t & 63;
    const int wn = w & 1, wm = w >> 1;
    const int l31 = l & 31, hi5 = l >> 5, l7 = l & 7, l3 = l >> 3;
    const int nbase = nt * 64 + wn * 32;

    // resident e1 B-fragments: n = nbase + l31, k = kk*16 + hi5*8
    bf16x8 e1f[4];
    {
        const __bf16* p = e1 + ((size_t)bc * NN + nbase + l31) * DD;
        #pragma unroll
        for (int kk = 0; kk < 4; ++kk)
            e1f[kk] = *(const bf16x8*)(p + kk * 16 + hi5 * 8);
    }

    f32x16 fz;                      // loop-invariant zero seed for S
    #pragma unroll
    for (int i = 0; i < 16; ++i) fz[i] = 0.f;

    f32x16 hacc[2];                 // [fb], partial over this wave's m-half
    #pragma unroll
    for (int fb = 0; fb < 2; ++fb)
        #pragma unroll
        for (int i = 0; i < 16; ++i) hacc[fb][i] = 0.f;

    const __bf16* e2h = e2 + (size_t)bc * NN * DD;
    const __bf16* vTh = vT + (size_t)bc * DD * NN;

    // stage K-tile kt: 8 chunks of 1KB per array; wave w does chunks 2w,2w+1.
    // 4 gload16 per wave per stage. lane l -> row ch*8+l3, phys slot l7,
    // global slot l7^l3 (LDS slot s holds global slot s^(row&7)).
    auto stage = [&](int buf, int kt) {
        #pragma unroll
        for (int ii = 0; ii < 2; ++ii) {
            const int ch  = w * 2 + ii;
            const int row = ch * 8 + l3;
            const int q   = l7 ^ l3;
            gload16(e2h + ((size_t)(kt * 64 + row)) * DD + q * 8, &e2t[buf * 4096 + ch * 512]);
            gload16(vTh + ((size_t)row) * NN + kt * 64 + q * 8, &vTt[buf * 4096 + ch * 512]);
        }
    };

    stage(0, 0);

    for (int kt = 0; kt < 32; ++kt) {
        const int buf = kt & 1;
        if (kt + 1 < 32) {
            stage(buf ^ 1, kt + 1);
            asm volatile("s_waitcnt vmcnt(4)" ::: "memory");   // kt's 4 landed
        } else {
            asm volatile("s_waitcnt vmcnt(0)" ::: "memory");
        }
        __builtin_amdgcn_sched_barrier(0);
        __builtin_amdgcn_s_barrier();      // all waves have kt's tile

        // ---- S^T phase: rows m = wm*32 + l31-range; cols n (lane) ----
        f32x16 s;
        __builtin_amdgcn_s_setprio(1);
        {
            const int slot0 = ((hi5) ^ l7) * 8;              // kk=0
            bf16x8 ef0 = *(const bf16x8*)&e2t[buf * 4096 + (wm * 32 + l31) * 64 + slot0];
            s = mfma32(ef0, e1f[0], fz);
        }
        #pragma unroll
        for (int kk = 1; kk < 4; ++kk) {
            const int slot = ((kk * 2 + hi5) ^ l7) * 8;
            bf16x8 ef = *(const bf16x8*)&e2t[buf * 4096 + (wm * 32 + l31) * 64 + slot];
            s = mfma32(ef, e1f[kk], s);
        }
        __builtin_amdgcn_s_setprio(0);

        // relu + pack quads: quad g holds m_local = 8g + 4*hi5 + 0..3
        i32x2 Q[4];
        #pragma unroll
        for (int g = 0; g < 4; ++g) {
            bf16x4 q0;
            #pragma unroll
            for (int r = 0; r < 4; ++r) {
                float v = s[4 * g + r];
                q0[r] = (__bf16)(v > 0.f ? v : 0.f);
            }
            Q[g] = __builtin_bit_cast(i32x2, q0);
        }

        // ---- PV phase: pf[j] = P[n][m = wm*32 + 16*kk2 + 8*hi5 + j] ----
        __builtin_amdgcn_s_setprio(1);
        #pragma unroll
        for (int kk2 = 0; kk2 < 2; ++kk2) {
            const int slot = ((wm * 4 + kk2 * 2 + hi5) ^ l7) * 8;
            bf16x8 vf0 = *(const bf16x8*)&vTt[buf * 4096 + (l31) * 64 + slot];
            bf16x8 vf1 = *(const bf16x8*)&vTt[buf * 4096 + (32 + l31) * 64 + slot];
            int a0 = Q[2 * kk2][0],     a1 = Q[2 * kk2][1];
            int b0 = Q[2 * kk2 + 1][0], b1 = Q[2 * kk2 + 1][1];
            plswap(a0, b0);
            plswap(a1, b1);
            i32x4 pfi = { a0, a1, b0, b1 };
            bf16x8 pf = __builtin_bit_cast(bf16x8, pfi);
            hacc[0] = mfma32(pf, vf0, hacc[0]);
            hacc[1] = mfma32(pf, vf1, hacc[1]);
        }
        __builtin_amdgcn_s_setprio(0);

        __builtin_amdgcn_s_barrier();      // all reads of buf done
    }

    // ---- epilogue: combine m-halves via LDS, add b3, store fp32 ----
    __syncthreads();                       // safe to reuse tile LDS as scratch
    if (wm == 1) {
        #pragma unroll
        for (int q = 0; q < 8; ++q) {
            f32x4 v;
            #pragma unroll
            for (int r = 0; r < 4; ++r) {
                const int idx = q * 4 + r;          // 0..31
                v[r] = hacc[idx >> 4][idx & 15];
            }
            *(f32x4*)&scratch[wn * 2048 + q * 256 + l * 4] = v;
        }
    }
    __syncthreads();
    if (wm == 0) {
        #pragma unroll
        for (int q = 0; q < 8; ++q) {
            f32x4 v = *(const f32x4*)&scratch[wn * 2048 + q * 256 + l * 4];
            #pragma unroll
            for (int r = 0; r < 4; ++r) {
                const int idx = q * 4 + r;
                hacc[idx >> 4][idx & 15] += v[r];
            }
        }
        const float bv0 = b3[l31], bv1 = b3[32 + l31];
        const size_t ob = ((size_t)bc * NN + nbase) * DD;
        #pragma unroll
        for (int reg = 0; reg < 16; ++reg) {
            const int n = (reg & 3) + 8 * (reg >> 2) + 4 * hi5;
            out[ob + (size_t)n * DD + l31]      = hacc[0][reg] + bv0;
            out[ob + (size_t)n * DD + 32 + l31] = hacc[1][reg] + bv1;
        }
    }
}

extern "C" void kernel_launch(void* const* d_in, const int* in_sizes, int n_in,
                              void* d_out, int out_size, void* d_ws, size_t ws_size,
                              hipStream_t stream) {
    const float* x  = (const float*)d_in[0];
    const float* W1 = (const float*)d_in[1];
    const float* b1 = (const float*)d_in[2];
    const float* W2 = (const float*)d_in[3];
    const float* b2 = (const float*)d_in[4];
    const float* W3 = (const float*)d_in[5];
    const float* b3 = (const float*)d_in[6];
    float* out = (float*)d_out;

    __bf16* e1 = (__bf16*)d_ws;                       // 8 MB
    __bf16* e2 = e1 + (size_t)BCH * NN * DD;          // 8 MB
    __bf16* vT = e2 + (size_t)BCH * NN * DD;          // 8 MB

    prep_kernel<<<dim3(1024), dim3(256), 0, stream>>>(x, W1, b1, W2, b2, W3, e1, e2, vT);
    fused_kernel<<<dim3(1024), dim3(256), 0, stream>>>(e1, e2, vT, b3, out);
}